// Round 1
// baseline (343.986 us; speedup 1.0000x reference)
//
#include <hip/hip_runtime.h>
#include <hip/hip_bf16.h>
#include <stdint.h>

// ---------------------------------------------------------------------------
// LinearFLHGS: per-group(64) symmetric int4 quant-dequant of x and w, then
// C = x_dq @ w_dq^T.  Strategy: quantize into bf16 (error << 0.151 threshold)
// in d_ws, then bf16 MFMA GEMM (128x128 tile, BK=64, 4 waves, global_load_lds
// staging with both-sides XOR swizzle for bank-conflict-free ds_read_b128).
// ---------------------------------------------------------------------------

typedef __bf16 bf16x8 __attribute__((ext_vector_type(8)));
typedef float f32x4 __attribute__((ext_vector_type(4)));

static __device__ __forceinline__ uint16_t f32_to_bf16_rne(float f) {
    uint32_t u = __float_as_uint(f);
    uint32_t r = (u + 0x7fffu + ((u >> 16) & 1u)) >> 16;
    return (uint16_t)r;
}

// Per-group-of-64 symmetric int4 quant + dequant -> bf16.
// Each lane handles 4 consecutive floats; 16 consecutive lanes = one group.
// total must be divisible by 4; (grid*block) waves each process 256-elem
// aligned chunks so the 16-lane shfl clusters align with groups.
__global__ void quant_kernel(const float* __restrict__ in,
                             uint16_t* __restrict__ out, int total4) {
    int nthreads = gridDim.x * blockDim.x;
    int t = blockIdx.x * blockDim.x + threadIdx.x;
    for (int i = t; i < total4; i += nthreads) {
        float4 v = ((const float4*)in)[i];
        float amax = fmaxf(fmaxf(fabsf(v.x), fabsf(v.y)),
                           fmaxf(fabsf(v.z), fabsf(v.w)));
        // reduce absmax over the 16-lane cluster (one group of 64 elements)
        #pragma unroll
        for (int m = 1; m <= 8; m <<= 1)
            amax = fmaxf(amax, __shfl_xor(amax, m, 64));
        float s = fmaxf(amax * (1.0f / 7.0f), 1e-8f);
        float q0 = fminf(fmaxf(rintf(v.x / s), -8.0f), 7.0f);
        float q1 = fminf(fmaxf(rintf(v.y / s), -8.0f), 7.0f);
        float q2 = fminf(fmaxf(rintf(v.z / s), -8.0f), 7.0f);
        float q3 = fminf(fmaxf(rintf(v.w / s), -8.0f), 7.0f);
        ushort4 o;
        o.x = f32_to_bf16_rne(q0 * s);
        o.y = f32_to_bf16_rne(q1 * s);
        o.z = f32_to_bf16_rne(q2 * s);
        o.w = f32_to_bf16_rne(q3 * s);
        ((ushort4*)out)[i] = o;
    }
}

#define BM 128
#define BN 128
#define BK 64

// C[m][n] = sum_k A[m][k]*B[n][k]   (A: MxK bf16, B: NxK bf16, C: MxN f32)
// LDS linear [128][64] bf16 per operand, staged via global_load_lds width=16.
// XOR swizzle (16B chunk index ^= row&7) applied on BOTH sides:
//   - stage: pre-swizzled GLOBAL source chunk, linear LDS dest (rule #21)
//   - read : swizzled ds_read address
__global__ __launch_bounds__(256, 2) void gemm_kernel(
        const uint16_t* __restrict__ A, const uint16_t* __restrict__ B,
        float* __restrict__ C, int M, int N, int K) {
    __shared__ uint16_t As[BM * BK];
    __shared__ uint16_t Bs[BN * BK];

    int nwg = gridDim.x;
    int bid = blockIdx.x;
    // XCD-aware swizzle (bijective since nwg % 8 == 0 here: 64*32=2048)
    int swz = bid;
    if ((nwg & 7) == 0) {
        int cpx = nwg >> 3;
        swz = (bid & 7) * cpx + (bid >> 3);
    }
    int nbn = N / BN;
    int bm = swz / nbn, bn = swz % nbn;

    int tid = threadIdx.x;
    int lane = tid & 63;
    int wid = tid >> 6;            // 0..3
    int wr = wid >> 1, wc = wid & 1;  // 2x2 wave grid, 64x64 per wave

    f32x4 acc[4][4] = {};

    const int rowA0 = bm * BM;
    const int colB0 = bn * BN;

    // staging: wave-instruction j covers 8 rows; lane l -> row rblk + (l>>3),
    // 16B chunk c=(l&7). Pre-swizzled global chunk = c ^ (row&7) = (l&7)^(l>>3).
    int srow = lane >> 3;                       // 0..7
    int scol = ((lane & 7) ^ (lane >> 3)) << 3; // swizzled k-offset (elements)

    for (int kt = 0; kt < K; kt += BK) {
        #pragma unroll
        for (int j = 0; j < 4; ++j) {
            int rblk = (wid * 4 + j) * 8;       // 8-row slab per wave-inst
            const uint16_t* ga =
                A + (size_t)(rowA0 + rblk + srow) * K + kt + scol;
            const uint16_t* gb =
                B + (size_t)(colB0 + rblk + srow) * K + kt + scol;
            uint16_t* la = As + rblk * BK;      // wave-uniform base
            uint16_t* lb = Bs + rblk * BK;
            __builtin_amdgcn_global_load_lds(
                (const __attribute__((address_space(1))) void*)ga,
                (__attribute__((address_space(3))) void*)la, 16, 0, 0);
            __builtin_amdgcn_global_load_lds(
                (const __attribute__((address_space(1))) void*)gb,
                (__attribute__((address_space(3))) void*)lb, 16, 0, 0);
        }
        __syncthreads();  // compiler drains vmcnt before s_barrier

        #pragma unroll
        for (int ks = 0; ks < 2; ++ks) {
            bf16x8 af[4], bfr[4];
            int rl = lane & 15;
            int c = ks * 4 + (lane >> 4);       // 16B chunk index 0..7
            #pragma unroll
            for (int mi = 0; mi < 4; ++mi) {
                int row = wr * 64 + mi * 16 + rl;
                af[mi] = *(const bf16x8*)(As + row * BK + ((c ^ (row & 7)) << 3));
            }
            #pragma unroll
            for (int ni = 0; ni < 4; ++ni) {
                int row = wc * 64 + ni * 16 + rl;
                bfr[ni] = *(const bf16x8*)(Bs + row * BK + ((c ^ (row & 7)) << 3));
            }
            #pragma unroll
            for (int mi = 0; mi < 4; ++mi)
                #pragma unroll
                for (int ni = 0; ni < 4; ++ni)
                    acc[mi][ni] = __builtin_amdgcn_mfma_f32_16x16x32_bf16(
                        af[mi], bfr[ni], acc[mi][ni], 0, 0, 0);
        }
        __syncthreads();
    }

    // epilogue: D mapping col = lane&15, row = (lane>>4)*4 + reg  [m89/m91]
    int cl = lane & 15;
    int rq = (lane >> 4) * 4;
    #pragma unroll
    for (int mi = 0; mi < 4; ++mi) {
        #pragma unroll
        for (int ni = 0; ni < 4; ++ni) {
            int row = rowA0 + wr * 64 + mi * 16 + rq;
            int col = colB0 + wc * 64 + ni * 16 + cl;
            float* cp = C + (size_t)row * N + col;
            #pragma unroll
            for (int r = 0; r < 4; ++r)
                cp[(size_t)r * N] = acc[mi][ni][r];
        }
    }
}

extern "C" void kernel_launch(void* const* d_in, const int* in_sizes, int n_in,
                              void* d_out, int out_size, void* d_ws, size_t ws_size,
                              hipStream_t stream) {
    const float* x = (const float*)d_in[0];
    const float* w = (const float*)d_in[1];
    float* out = (float*)d_out;

    const int K = 4096;
    const int T = in_sizes[0] / K;   // 8192
    const int O = in_sizes[1] / K;   // 4096

    uint16_t* xq = (uint16_t*)d_ws;                                  // T*K bf16
    uint16_t* wq = (uint16_t*)((char*)d_ws + (size_t)T * K * 2);     // O*K bf16
    // needs (T+O)*K*2 = 96 MB of workspace

    quant_kernel<<<2048, 256, 0, stream>>>(x, xq, (T * K) >> 2);
    quant_kernel<<<2048, 256, 0, stream>>>(w, wq, (O * K) >> 2);

    int nwg = (T / BM) * (O / BN);   // 64*32 = 2048
    gemm_kernel<<<nwg, 256, 0, stream>>>(xq, wq, out, T, O, K);
}

// Round 2
// 306.176 us; speedup vs baseline: 1.1235x; 1.1235x over previous
//
#include <hip/hip_runtime.h>
#include <hip/hip_bf16.h>
#include <stdint.h>

// ---------------------------------------------------------------------------
// LinearFLHGS: per-group(64) symmetric int4 quant-dequant of x and w, then
// C = x_dq @ w_dq^T.  Round 2: 256x256 8-phase GEMM (T2+T3+T4+T5 stack):
// 8 waves, BK=64, 128 KiB LDS double-buffer, counted vmcnt(4) (never 0 in
// steady state), raw s_barrier, setprio-wrapped MFMA clusters, both-sides
// XOR swizzle (proven 0 bank conflicts in round 1).
// ---------------------------------------------------------------------------

typedef __bf16 bf16x8 __attribute__((ext_vector_type(8)));
typedef float f32x4 __attribute__((ext_vector_type(4)));

static __device__ __forceinline__ uint16_t f32_to_bf16_rne(float f) {
    uint32_t u = __float_as_uint(f);
    uint32_t r = (u + 0x7fffu + ((u >> 16) & 1u)) >> 16;
    return (uint16_t)r;
}

// Per-group-of-64 symmetric int4 quant + dequant -> bf16.
__global__ void quant_kernel(const float* __restrict__ in,
                             uint16_t* __restrict__ out, int total4) {
    int nthreads = gridDim.x * blockDim.x;
    int t = blockIdx.x * blockDim.x + threadIdx.x;
    for (int i = t; i < total4; i += nthreads) {
        float4 v = ((const float4*)in)[i];
        float amax = fmaxf(fmaxf(fabsf(v.x), fabsf(v.y)),
                           fmaxf(fabsf(v.z), fabsf(v.w)));
        #pragma unroll
        for (int m = 1; m <= 8; m <<= 1)
            amax = fmaxf(amax, __shfl_xor(amax, m, 64));
        float s = fmaxf(amax * (1.0f / 7.0f), 1e-8f);
        float q0 = fminf(fmaxf(rintf(v.x / s), -8.0f), 7.0f);
        float q1 = fminf(fmaxf(rintf(v.y / s), -8.0f), 7.0f);
        float q2 = fminf(fmaxf(rintf(v.z / s), -8.0f), 7.0f);
        float q3 = fminf(fmaxf(rintf(v.w / s), -8.0f), 7.0f);
        ushort4 o;
        o.x = f32_to_bf16_rne(q0 * s);
        o.y = f32_to_bf16_rne(q1 * s);
        o.z = f32_to_bf16_rne(q2 * s);
        o.w = f32_to_bf16_rne(q3 * s);
        ((ushort4*)out)[i] = o;
    }
}

#define BM 256
#define BN 256
#define BK 64

// 8-phase 256^2 GEMM:  C[m][n] = sum_k A[m][k]*B[n][k]
// A: MxK bf16, B: NxK bf16 (both quant-dequant'd), C: MxN f32.
__global__ __launch_bounds__(512, 2) void gemm8_kernel(
        const uint16_t* __restrict__ A, const uint16_t* __restrict__ B,
        float* __restrict__ C, int M, int N, int K) {
    // [buf][half][128 rows][64 k] bf16 = 16 KB each; total 128 KB
    __shared__ uint16_t As[2][2][128 * 64];
    __shared__ uint16_t Bs[2][2][128 * 64];

    const int NTt = K >> 6;   // K-tiles of 64

    int nwg = gridDim.x;
    int bid = blockIdx.x;
    int swz = bid;
    if ((nwg & 7) == 0) {     // bijective XCD swizzle
        int cpx = nwg >> 3;
        swz = (bid & 7) * cpx + (bid >> 3);
    }
    int nbn = N / BN;
    int bm = swz / nbn, bn = swz % nbn;

    int tid = threadIdx.x;
    int lane = tid & 63;
    int wid = tid >> 6;       // 0..7
    int wm = wid >> 2;        // 0..1 : 128-row band
    int wn = wid & 3;         // 0..3 : 64-col band

    const int rowA0 = bm * BM;
    const int colB0 = bn * BN;

    // --- staging constants (linear LDS dest, inverse-swizzled global src) ---
    int srow = lane >> 3;                        // 0..7
    int scol = ((lane & 7) ^ (lane >> 3)) << 3;  // swizzled k elem offset

    // --- read constants (swizzled ds_read addr) ---
    int rl = lane & 15;
    int cg = lane >> 4;                          // 0..3
    int coff[2];
    coff[0] = ((0 + cg) ^ (rl & 7)) << 3;        // ks=0: logical chunk cg
    coff[1] = ((4 + cg) ^ (rl & 7)) << 3;        // ks=1: logical chunk 4+cg

    f32x4 acc[8][4] = {};

    // each wave stages its own 16 rows per half-tile (2 insts x 8 rows)
    auto stageA = [&](int buf, int half, int t) {
        #pragma unroll
        for (int j = 0; j < 2; ++j) {
            int rowin = wid * 16 + j * 8;
            const uint16_t* g = A + (size_t)(rowA0 + half * 128 + rowin + srow) * K
                                  + t * 64 + scol;
            uint16_t* l = &As[buf][half][rowin * 64];
            __builtin_amdgcn_global_load_lds(
                (const __attribute__((address_space(1))) void*)g,
                (__attribute__((address_space(3))) void*)l, 16, 0, 0);
        }
    };
    auto stageB = [&](int buf, int half, int t) {
        #pragma unroll
        for (int j = 0; j < 2; ++j) {
            int rowin = wid * 16 + j * 8;
            const uint16_t* g = B + (size_t)(colB0 + half * 128 + rowin + srow) * K
                                  + t * 64 + scol;
            uint16_t* l = &Bs[buf][half][rowin * 64];
            __builtin_amdgcn_global_load_lds(
                (const __attribute__((address_space(1))) void*)g,
                (__attribute__((address_space(3))) void*)l, 16, 0, 0);
        }
    };

    // ---- prologue: K0 fully + B(1); wait K0 landed, leave B(1) in flight ----
    stageA(0, 0, 0); stageA(0, 1, 0);
    stageB(0, 0, 0); stageB(0, 1, 0);
    if (NTt > 1) {
        stageB(1, 0, 1); stageB(1, 1, 1);
        asm volatile("s_waitcnt vmcnt(4)" ::: "memory");
    } else {
        asm volatile("s_waitcnt vmcnt(0)" ::: "memory");
    }
    asm volatile("" ::: "memory");
    __builtin_amdgcn_s_barrier();
    asm volatile("" ::: "memory");

    bf16x8 aLo[4][2], aHi[4][2], bLo[2][2], bHi[2][2];
    const int bhalf = wn >> 1;
    const int brow0 = (wn & 1) * 64;

#define PHASE_MID() \
    asm volatile("" ::: "memory"); \
    __builtin_amdgcn_s_barrier(); \
    asm volatile("s_waitcnt lgkmcnt(0)" ::: "memory"); \
    __builtin_amdgcn_sched_barrier(0); \
    __builtin_amdgcn_s_setprio(1);

#define PHASE_END() \
    __builtin_amdgcn_s_setprio(0); \
    asm volatile("" ::: "memory"); \
    __builtin_amdgcn_s_barrier(); \
    asm volatile("" ::: "memory");

    for (int t = 0; t < NTt; ++t) {
        int cb = t & 1, nb = cb ^ 1;

        // ---- phase 1: Q(mLo,nLo) — read aLo(8) + bLo(4); stage A(t+1)h0 ----
        #pragma unroll
        for (int mi = 0; mi < 4; ++mi)
            #pragma unroll
            for (int ks = 0; ks < 2; ++ks)
                aLo[mi][ks] = *(const bf16x8*)&As[cb][wm][(mi * 16 + rl) * 64 + coff[ks]];
        #pragma unroll
        for (int ni = 0; ni < 2; ++ni)
            #pragma unroll
            for (int ks = 0; ks < 2; ++ks)
                bLo[ni][ks] = *(const bf16x8*)&Bs[cb][bhalf][(brow0 + ni * 16 + rl) * 64 + coff[ks]];
        if (t + 1 < NTt) stageA(nb, 0, t + 1);
        PHASE_MID();
        #pragma unroll
        for (int mi = 0; mi < 4; ++mi)
            #pragma unroll
            for (int ni = 0; ni < 2; ++ni)
                #pragma unroll
                for (int ks = 0; ks < 2; ++ks)
                    acc[mi][ni] = __builtin_amdgcn_mfma_f32_16x16x32_bf16(
                        aLo[mi][ks], bLo[ni][ks], acc[mi][ni], 0, 0, 0);
        PHASE_END();

        // ---- phase 2: Q(mLo,nHi) — read bHi(4); stage A(t+1)h1 ----
        #pragma unroll
        for (int ni = 0; ni < 2; ++ni)
            #pragma unroll
            for (int ks = 0; ks < 2; ++ks)
                bHi[ni][ks] = *(const bf16x8*)&Bs[cb][bhalf][(brow0 + (ni + 2) * 16 + rl) * 64 + coff[ks]];
        if (t + 1 < NTt) stageA(nb, 1, t + 1);
        PHASE_MID();
        #pragma unroll
        for (int mi = 0; mi < 4; ++mi)
            #pragma unroll
            for (int ni = 0; ni < 2; ++ni)
                #pragma unroll
                for (int ks = 0; ks < 2; ++ks)
                    acc[mi][ni + 2] = __builtin_amdgcn_mfma_f32_16x16x32_bf16(
                        aLo[mi][ks], bHi[ni][ks], acc[mi][ni + 2], 0, 0, 0);
        PHASE_END();

        // ---- phase 3: Q(mHi,nLo) — read aHi(8); stage B(t+2)h0 (into cb) ----
        #pragma unroll
        for (int mi = 0; mi < 4; ++mi)
            #pragma unroll
            for (int ks = 0; ks < 2; ++ks)
                aHi[mi][ks] = *(const bf16x8*)&As[cb][wm][((mi + 4) * 16 + rl) * 64 + coff[ks]];
        if (t + 2 < NTt) stageB(cb, 0, t + 2);
        PHASE_MID();
        #pragma unroll
        for (int mi = 0; mi < 4; ++mi)
            #pragma unroll
            for (int ni = 0; ni < 2; ++ni)
                #pragma unroll
                for (int ks = 0; ks < 2; ++ks)
                    acc[mi + 4][ni] = __builtin_amdgcn_mfma_f32_16x16x32_bf16(
                        aHi[mi][ks], bLo[ni][ks], acc[mi + 4][ni], 0, 0, 0);
        PHASE_END();

        // ---- phase 4: Q(mHi,nHi) — no reads; stage B(t+2)h1; vmcnt(4) ----
        if (t + 2 < NTt) stageB(cb, 1, t + 2);
        asm volatile("" ::: "memory");
        __builtin_amdgcn_s_barrier();
        __builtin_amdgcn_sched_barrier(0);
        __builtin_amdgcn_s_setprio(1);
        #pragma unroll
        for (int mi = 0; mi < 4; ++mi)
            #pragma unroll
            for (int ni = 0; ni < 2; ++ni)
                #pragma unroll
                for (int ks = 0; ks < 2; ++ks)
                    acc[mi + 4][ni + 2] = __builtin_amdgcn_mfma_f32_16x16x32_bf16(
                        aHi[mi][ks], bHi[ni][ks], acc[mi + 4][ni + 2], 0, 0, 0);
        __builtin_amdgcn_s_setprio(0);
        // counted drain: K(t+1) fully landed, B(t+2) stays in flight
        if (t + 2 < NTt) asm volatile("s_waitcnt vmcnt(4)" ::: "memory");
        else             asm volatile("s_waitcnt vmcnt(0)" ::: "memory");
        asm volatile("" ::: "memory");
        __builtin_amdgcn_s_barrier();
        asm volatile("" ::: "memory");
    }

    // ---- epilogue: D map col = lane&15, row = (lane>>4)*4 + reg ----
    int cl = lane & 15;
    int rq = (lane >> 4) * 4;
    #pragma unroll
    for (int mi = 0; mi < 8; ++mi) {
        #pragma unroll
        for (int ni = 0; ni < 4; ++ni) {
            int row = rowA0 + wm * 128 + mi * 16 + rq;
            int col = colB0 + wn * 64 + ni * 16 + cl;
            float* cp = C + (size_t)row * N + col;
            #pragma unroll
            for (int r = 0; r < 4; ++r)
                cp[(size_t)r * N] = acc[mi][ni][r];
        }
    }
#undef PHASE_MID
#undef PHASE_END
}

extern "C" void kernel_launch(void* const* d_in, const int* in_sizes, int n_in,
                              void* d_out, int out_size, void* d_ws, size_t ws_size,
                              hipStream_t stream) {
    const float* x = (const float*)d_in[0];
    const float* w = (const float*)d_in[1];
    float* out = (float*)d_out;

    const int K = 4096;
    const int T = in_sizes[0] / K;   // 8192
    const int O = in_sizes[1] / K;   // 4096

    uint16_t* xq = (uint16_t*)d_ws;                                  // T*K bf16
    uint16_t* wq = (uint16_t*)((char*)d_ws + (size_t)T * K * 2);     // O*K bf16

    quant_kernel<<<2048, 256, 0, stream>>>(x, xq, (T * K) >> 2);
    quant_kernel<<<2048, 256, 0, stream>>>(w, wq, (O * K) >> 2);

    int nwg = (T / BM) * (O / BN);   // 32*16 = 512
    gemm8_kernel<<<nwg, 512, 0, stream>>>(xq, wq, out, T, O, K);
}

// Round 3
// 299.557 us; speedup vs baseline: 1.1483x; 1.0221x over previous
//
#include <hip/hip_runtime.h>
#include <hip/hip_bf16.h>
#include <stdint.h>

// ---------------------------------------------------------------------------
// LinearFLHGS: per-group(64) symmetric int4 quant-dequant of x and w, then
// C = x_dq @ w_dq^T.  Round 3: 256x256 GEMM, 2 barriers per K-tile.
// All 24 fragment ds_reads issued at tile start (compiler emits counted
// lgkmcnt => reads overlap MFMA); Q1/Q2/Q3 clusters back-to-back; barrier;
// stage K-tile t+2 (2-deep, counted vmcnt(8) across tile boundary); Q4
// hides stage issue; tile-end barrier.  Swizzle + epilogue proven rounds 1-2.
// ---------------------------------------------------------------------------

typedef __bf16 bf16x8 __attribute__((ext_vector_type(8)));
typedef float f32x4 __attribute__((ext_vector_type(4)));

static __device__ __forceinline__ uint16_t f32_to_bf16_rne(float f) {
    uint32_t u = __float_as_uint(f);
    uint32_t r = (u + 0x7fffu + ((u >> 16) & 1u)) >> 16;
    return (uint16_t)r;
}

// Per-group-of-64 symmetric int4 quant + dequant -> bf16.
__global__ void quant_kernel(const float* __restrict__ in,
                             uint16_t* __restrict__ out, int total4) {
    int nthreads = gridDim.x * blockDim.x;
    int t = blockIdx.x * blockDim.x + threadIdx.x;
    for (int i = t; i < total4; i += nthreads) {
        float4 v = ((const float4*)in)[i];
        float amax = fmaxf(fmaxf(fabsf(v.x), fabsf(v.y)),
                           fmaxf(fabsf(v.z), fabsf(v.w)));
        #pragma unroll
        for (int m = 1; m <= 8; m <<= 1)
            amax = fmaxf(amax, __shfl_xor(amax, m, 64));
        float s = fmaxf(amax * (1.0f / 7.0f), 1e-8f);
        float q0 = fminf(fmaxf(rintf(v.x / s), -8.0f), 7.0f);
        float q1 = fminf(fmaxf(rintf(v.y / s), -8.0f), 7.0f);
        float q2 = fminf(fmaxf(rintf(v.z / s), -8.0f), 7.0f);
        float q3 = fminf(fmaxf(rintf(v.w / s), -8.0f), 7.0f);
        ushort4 o;
        o.x = f32_to_bf16_rne(q0 * s);
        o.y = f32_to_bf16_rne(q1 * s);
        o.z = f32_to_bf16_rne(q2 * s);
        o.w = f32_to_bf16_rne(q3 * s);
        ((ushort4*)out)[i] = o;
    }
}

#define BM 256
#define BN 256
#define BK 64

#define FENCE() asm volatile("" ::: "memory")

__global__ __launch_bounds__(512, 2) void gemm_kernel(
        const uint16_t* __restrict__ A, const uint16_t* __restrict__ B,
        float* __restrict__ C, int M, int N, int K) {
    // [buf][half][128 rows][64 k] bf16 = 16 KB each; total 128 KB
    __shared__ uint16_t As[2][2][128 * 64];
    __shared__ uint16_t Bs[2][2][128 * 64];

    const int NTt = K >> 6;   // 64 K-tiles

    int nwg = gridDim.x;
    int bid = blockIdx.x;
    int swz = bid;
    if ((nwg & 7) == 0) {     // bijective XCD swizzle (nwg=512)
        int cpx = nwg >> 3;
        swz = (bid & 7) * cpx + (bid >> 3);
    }
    int nbn = N / BN;
    int bm = swz / nbn, bn = swz % nbn;

    int tid = threadIdx.x;
    int lane = tid & 63;
    int wid = tid >> 6;       // 0..7
    int wm = wid >> 2;        // 0..1 : 128-row band of A
    int wn = wid & 3;         // 0..3 : 64-col band of B

    const int rowA0 = bm * BM;
    const int colB0 = bn * BN;

    // staging: linear LDS dest, inverse-swizzled global src (rule #21)
    int srow = lane >> 3;                        // 0..7
    int scol = ((lane & 7) ^ (lane >> 3)) << 3;  // swizzled k elem offset

    // reads: swizzled ds_read addr (proven 0 bank conflicts)
    int rl = lane & 15;
    int cg = lane >> 4;                          // 0..3
    int coff[2];
    coff[0] = ((0 + cg) ^ (rl & 7)) << 3;
    coff[1] = ((4 + cg) ^ (rl & 7)) << 3;

    f32x4 acc[8][4] = {};

    auto stageA = [&](int buf, int half, int t) {
        #pragma unroll
        for (int j = 0; j < 2; ++j) {
            int rowin = wid * 16 + j * 8;
            const uint16_t* g = A + (size_t)(rowA0 + half * 128 + rowin + srow) * K
                                  + t * 64 + scol;
            uint16_t* l = &As[buf][half][rowin * 64];
            __builtin_amdgcn_global_load_lds(
                (const __attribute__((address_space(1))) void*)g,
                (__attribute__((address_space(3))) void*)l, 16, 0, 0);
        }
    };
    auto stageB = [&](int buf, int half, int t) {
        #pragma unroll
        for (int j = 0; j < 2; ++j) {
            int rowin = wid * 16 + j * 8;
            const uint16_t* g = B + (size_t)(colB0 + half * 128 + rowin + srow) * K
                                  + t * 64 + scol;
            uint16_t* l = &Bs[buf][half][rowin * 64];
            __builtin_amdgcn_global_load_lds(
                (const __attribute__((address_space(1))) void*)g,
                (__attribute__((address_space(3))) void*)l, 16, 0, 0);
        }
    };

    // ---- prologue: stage K-tiles 0 and 1; wait tile 0 only ----
    stageA(0, 0, 0); stageA(0, 1, 0);
    stageB(0, 0, 0); stageB(0, 1, 0);
    if (NTt > 1) {
        stageA(1, 0, 1); stageA(1, 1, 1);
        stageB(1, 0, 1); stageB(1, 1, 1);
        asm volatile("s_waitcnt vmcnt(8)" ::: "memory");
    } else {
        asm volatile("s_waitcnt vmcnt(0)" ::: "memory");
    }
    FENCE(); __builtin_amdgcn_s_barrier(); FENCE();

    const int bhalf = wn >> 1;
    const int brow0 = (wn & 1) * 64;

    for (int t = 0; t < NTt; ++t) {
        int cb = t & 1;
        const bool more = (t + 2 < NTt);

        // ---- issue ALL fragment reads; compiler emits counted lgkmcnt ----
        bf16x8 aLo[4][2], bLo[2][2], bHi[2][2], aHi[4][2];
        #pragma unroll
        for (int mi = 0; mi < 4; ++mi)
            #pragma unroll
            for (int ks = 0; ks < 2; ++ks)
                aLo[mi][ks] = *(const bf16x8*)&As[cb][wm][(mi * 16 + rl) * 64 + coff[ks]];
        #pragma unroll
        for (int ni = 0; ni < 2; ++ni)
            #pragma unroll
            for (int ks = 0; ks < 2; ++ks)
                bLo[ni][ks] = *(const bf16x8*)&Bs[cb][bhalf][(brow0 + ni * 16 + rl) * 64 + coff[ks]];
        #pragma unroll
        for (int ni = 0; ni < 2; ++ni)
            #pragma unroll
            for (int ks = 0; ks < 2; ++ks)
                bHi[ni][ks] = *(const bf16x8*)&Bs[cb][bhalf][(brow0 + (ni + 2) * 16 + rl) * 64 + coff[ks]];
        #pragma unroll
        for (int mi = 0; mi < 4; ++mi)
            #pragma unroll
            for (int ks = 0; ks < 2; ++ks)
                aHi[mi][ks] = *(const bf16x8*)&As[cb][wm][((mi + 4) * 16 + rl) * 64 + coff[ks]];

        // ---- Q1: aLo x bLo ----
        __builtin_amdgcn_s_setprio(1);
        #pragma unroll
        for (int mi = 0; mi < 4; ++mi)
            #pragma unroll
            for (int ni = 0; ni < 2; ++ni)
                #pragma unroll
                for (int ks = 0; ks < 2; ++ks)
                    acc[mi][ni] = __builtin_amdgcn_mfma_f32_16x16x32_bf16(
                        aLo[mi][ks], bLo[ni][ks], acc[mi][ni], 0, 0, 0);
        __builtin_amdgcn_s_setprio(0);

        // ---- Q2: aLo x bHi ----
        __builtin_amdgcn_s_setprio(1);
        #pragma unroll
        for (int mi = 0; mi < 4; ++mi)
            #pragma unroll
            for (int ni = 0; ni < 2; ++ni)
                #pragma unroll
                for (int ks = 0; ks < 2; ++ks)
                    acc[mi][ni + 2] = __builtin_amdgcn_mfma_f32_16x16x32_bf16(
                        aLo[mi][ks], bHi[ni][ks], acc[mi][ni + 2], 0, 0, 0);
        __builtin_amdgcn_s_setprio(0);

        // ---- Q3: aHi x bLo ----
        __builtin_amdgcn_s_setprio(1);
        #pragma unroll
        for (int mi = 0; mi < 4; ++mi)
            #pragma unroll
            for (int ni = 0; ni < 2; ++ni)
                #pragma unroll
                for (int ks = 0; ks < 2; ++ks)
                    acc[mi + 4][ni] = __builtin_amdgcn_mfma_f32_16x16x32_bf16(
                        aHi[mi][ks], bLo[ni][ks], acc[mi + 4][ni], 0, 0, 0);
        __builtin_amdgcn_s_setprio(0);

        // ---- barrier: all waves finished ALL reads of buf[cb] ----
        FENCE(); __builtin_amdgcn_s_barrier(); FENCE();

        // ---- stage K-tile t+2 into buf[cb] (now dead); issue hides under Q4
        if (more) {
            stageA(cb, 0, t + 2); stageA(cb, 1, t + 2);
            stageB(cb, 0, t + 2); stageB(cb, 1, t + 2);
        }
        __builtin_amdgcn_sched_barrier(0);  // pin stage issue before Q4

        // ---- Q4: aHi x bHi ----
        __builtin_amdgcn_s_setprio(1);
        #pragma unroll
        for (int mi = 0; mi < 4; ++mi)
            #pragma unroll
            for (int ni = 0; ni < 2; ++ni)
                #pragma unroll
                for (int ks = 0; ks < 2; ++ks)
                    acc[mi + 4][ni + 2] = __builtin_amdgcn_mfma_f32_16x16x32_bf16(
                        aHi[mi][ks], bHi[ni][ks], acc[mi + 4][ni + 2], 0, 0, 0);
        __builtin_amdgcn_s_setprio(0);

        // ---- counted drain: K(t+1) landed; K(t+2) stays in flight ----
        if (more) asm volatile("s_waitcnt vmcnt(8)" ::: "memory");
        else      asm volatile("s_waitcnt vmcnt(0)" ::: "memory");
        FENCE(); __builtin_amdgcn_s_barrier(); FENCE();
    }

    // ---- epilogue: D map col = lane&15, row = (lane>>4)*4 + reg ----
    int cl = lane & 15;
    int rq = (lane >> 4) * 4;
    #pragma unroll
    for (int mi = 0; mi < 8; ++mi) {
        #pragma unroll
        for (int ni = 0; ni < 4; ++ni) {
            int row = rowA0 + wm * 128 + mi * 16 + rq;
            int col = colB0 + wn * 64 + ni * 16 + cl;
            float* cp = C + (size_t)row * N + col;
            #pragma unroll
            for (int r = 0; r < 4; ++r)
                cp[(size_t)r * N] = acc[mi][ni][r];
        }
    }
}

extern "C" void kernel_launch(void* const* d_in, const int* in_sizes, int n_in,
                              void* d_out, int out_size, void* d_ws, size_t ws_size,
                              hipStream_t stream) {
    const float* x = (const float*)d_in[0];
    const float* w = (const float*)d_in[1];
    float* out = (float*)d_out;

    const int K = 4096;
    const int T = in_sizes[0] / K;   // 8192
    const int O = in_sizes[1] / K;   // 4096

    uint16_t* xq = (uint16_t*)d_ws;                                  // T*K bf16
    uint16_t* wq = (uint16_t*)((char*)d_ws + (size_t)T * K * 2);     // O*K bf16

    quant_kernel<<<2048, 256, 0, stream>>>(x, xq, (T * K) >> 2);
    quant_kernel<<<2048, 256, 0, stream>>>(w, wq, (O * K) >> 2);

    int nwg = (T / BM) * (O / BN);   // 32*16 = 512
    gemm_kernel<<<nwg, 512, 0, stream>>>(xq, wq, out, T, O, K);
}

// Round 4
// 286.814 us; speedup vs baseline: 1.1993x; 1.0444x over previous
//
#include <hip/hip_runtime.h>
#include <hip/hip_bf16.h>
#include <stdint.h>

// ---------------------------------------------------------------------------
// LinearFLHGS: per-group(64) symmetric int4 quant-dequant of x and w, then
// C = x_dq @ w_dq^T.  Round 4: LDS-pipe-utilization attack.  256x256, 8 waves,
// BK=64, double-buffered.  Per K-tile the read bursts are interleaved with
// MFMA quadrants (sched_barrier(0) fences pin the interleave) so the LDS pipe
// stays busy while MFMAs drain; stage writes hide under Q3/Q4.  Counted
// vmcnt(8), 2 barriers/tile (race-ledger identical to round 3, absmax-proven).
// Quant fix: s = amax / 7.0f exactly (was *(1/7): 1-ulp scale diff flips
// round() at halfway points vs the numpy reference).
// ---------------------------------------------------------------------------

typedef __bf16 bf16x8 __attribute__((ext_vector_type(8)));
typedef float f32x4 __attribute__((ext_vector_type(4)));

static __device__ __forceinline__ uint16_t f32_to_bf16_rne(float f) {
    uint32_t u = __float_as_uint(f);
    uint32_t r = (u + 0x7fffu + ((u >> 16) & 1u)) >> 16;
    return (uint16_t)r;
}

__global__ void quant_kernel(const float* __restrict__ in,
                             uint16_t* __restrict__ out, int total4) {
    int nthreads = gridDim.x * blockDim.x;
    int t = blockIdx.x * blockDim.x + threadIdx.x;
    for (int i = t; i < total4; i += nthreads) {
        float4 v = ((const float4*)in)[i];
        float amax = fmaxf(fmaxf(fabsf(v.x), fabsf(v.y)),
                           fmaxf(fabsf(v.z), fabsf(v.w)));
        #pragma unroll
        for (int m = 1; m <= 8; m <<= 1)
            amax = fmaxf(amax, __shfl_xor(amax, m, 64));
        float s = fmaxf(amax / 7.0f, 1e-8f);   // exact match to reference
        float inv = 1.0f / s;                   // q = rint(x/s): use mul by 1/s?
        // NO: x*(1/s) can differ from x/s at the .5 boundary. Divide exactly.
        (void)inv;
        float q0 = fminf(fmaxf(rintf(v.x / s), -8.0f), 7.0f);
        float q1 = fminf(fmaxf(rintf(v.y / s), -8.0f), 7.0f);
        float q2 = fminf(fmaxf(rintf(v.z / s), -8.0f), 7.0f);
        float q3 = fminf(fmaxf(rintf(v.w / s), -8.0f), 7.0f);
        ushort4 o;
        o.x = f32_to_bf16_rne(q0 * s);
        o.y = f32_to_bf16_rne(q1 * s);
        o.z = f32_to_bf16_rne(q2 * s);
        o.w = f32_to_bf16_rne(q3 * s);
        ((ushort4*)out)[i] = o;
    }
}

#define BM 256
#define BN 256
#define BK 64

#define FENCE() asm volatile("" ::: "memory")
#define SB0()   __builtin_amdgcn_sched_barrier(0)

__global__ __launch_bounds__(512, 2) void gemm_kernel(
        const uint16_t* __restrict__ A, const uint16_t* __restrict__ B,
        float* __restrict__ C, int M, int N, int K) {
    __shared__ uint16_t As[2][2][128 * 64];
    __shared__ uint16_t Bs[2][2][128 * 64];

    const int NTt = K >> 6;

    int nwg = gridDim.x;
    int bid = blockIdx.x;
    int swz = bid;
    if ((nwg & 7) == 0) {
        int cpx = nwg >> 3;
        swz = (bid & 7) * cpx + (bid >> 3);
    }
    int nbn = N / BN;
    int bm = swz / nbn, bn = swz % nbn;

    int tid = threadIdx.x;
    int lane = tid & 63;
    int wid = tid >> 6;
    int wm = wid >> 2;
    int wn = wid & 3;

    const int rowA0 = bm * BM;
    const int colB0 = bn * BN;

    int srow = lane >> 3;
    int scol = ((lane & 7) ^ (lane >> 3)) << 3;

    int rl = lane & 15;
    int cg = lane >> 4;
    int coff[2];
    coff[0] = ((0 + cg) ^ (rl & 7)) << 3;
    coff[1] = ((4 + cg) ^ (rl & 7)) << 3;

    f32x4 acc[8][4] = {};

    auto stageA = [&](int buf, int half, int t) {
        #pragma unroll
        for (int j = 0; j < 2; ++j) {
            int rowin = wid * 16 + j * 8;
            const uint16_t* g = A + (size_t)(rowA0 + half * 128 + rowin + srow) * K
                                  + t * 64 + scol;
            uint16_t* l = &As[buf][half][rowin * 64];
            __builtin_amdgcn_global_load_lds(
                (const __attribute__((address_space(1))) void*)g,
                (__attribute__((address_space(3))) void*)l, 16, 0, 0);
        }
    };
    auto stageB = [&](int buf, int half, int t) {
        #pragma unroll
        for (int j = 0; j < 2; ++j) {
            int rowin = wid * 16 + j * 8;
            const uint16_t* g = B + (size_t)(colB0 + half * 128 + rowin + srow) * K
                                  + t * 64 + scol;
            uint16_t* l = &Bs[buf][half][rowin * 64];
            __builtin_amdgcn_global_load_lds(
                (const __attribute__((address_space(1))) void*)g,
                (__attribute__((address_space(3))) void*)l, 16, 0, 0);
        }
    };

    stageA(0, 0, 0); stageA(0, 1, 0);
    stageB(0, 0, 0); stageB(0, 1, 0);
    if (NTt > 1) {
        stageA(1, 0, 1); stageA(1, 1, 1);
        stageB(1, 0, 1); stageB(1, 1, 1);
        asm volatile("s_waitcnt vmcnt(8)" ::: "memory");
    } else {
        asm volatile("s_waitcnt vmcnt(0)" ::: "memory");
    }
    FENCE(); __builtin_amdgcn_s_barrier(); FENCE();

    const int bhalf = wn >> 1;
    const int brow0 = (wn & 1) * 64;

    for (int t = 0; t < NTt; ++t) {
        int cb = t & 1;
        const bool more = (t + 2 < NTt);

        bf16x8 aLo[4][2], bLo[2][2], bHi[2][2], aHi[4][2];

        // ---- burst 1: aLo (8) + bLo (4) — Q1's operands ----
        #pragma unroll
        for (int mi = 0; mi < 4; ++mi)
            #pragma unroll
            for (int ks = 0; ks < 2; ++ks)
                aLo[mi][ks] = *(const bf16x8*)&As[cb][wm][(mi * 16 + rl) * 64 + coff[ks]];
        #pragma unroll
        for (int ni = 0; ni < 2; ++ni)
            #pragma unroll
            for (int ks = 0; ks < 2; ++ks)
                bLo[ni][ks] = *(const bf16x8*)&Bs[cb][bhalf][(brow0 + ni * 16 + rl) * 64 + coff[ks]];
        SB0();

        // ---- Q1: aLo x bLo (compiler waits only on burst-1 via counted lgkm)
        __builtin_amdgcn_s_setprio(1);
        #pragma unroll
        for (int mi = 0; mi < 4; ++mi)
            #pragma unroll
            for (int ni = 0; ni < 2; ++ni)
                #pragma unroll
                for (int ks = 0; ks < 2; ++ks)
                    acc[mi][ni] = __builtin_amdgcn_mfma_f32_16x16x32_bf16(
                        aLo[mi][ks], bLo[ni][ks], acc[mi][ni], 0, 0, 0);
        __builtin_amdgcn_s_setprio(0);
        SB0();

        // ---- burst 2: bHi (4) + aHi (8) — drains under Q1/Q2 ----
        #pragma unroll
        for (int ni = 0; ni < 2; ++ni)
            #pragma unroll
            for (int ks = 0; ks < 2; ++ks)
                bHi[ni][ks] = *(const bf16x8*)&Bs[cb][bhalf][(brow0 + (ni + 2) * 16 + rl) * 64 + coff[ks]];
        #pragma unroll
        for (int mi = 0; mi < 4; ++mi)
            #pragma unroll
            for (int ks = 0; ks < 2; ++ks)
                aHi[mi][ks] = *(const bf16x8*)&As[cb][wm][((mi + 4) * 16 + rl) * 64 + coff[ks]];
        SB0();

        // ---- Q2: aLo x bHi ----
        __builtin_amdgcn_s_setprio(1);
        #pragma unroll
        for (int mi = 0; mi < 4; ++mi)
            #pragma unroll
            for (int ni = 0; ni < 2; ++ni)
                #pragma unroll
                for (int ks = 0; ks < 2; ++ks)
                    acc[mi][ni + 2] = __builtin_amdgcn_mfma_f32_16x16x32_bf16(
                        aLo[mi][ks], bHi[ni][ks], acc[mi][ni + 2], 0, 0, 0);
        __builtin_amdgcn_s_setprio(0);

        // ---- all reads of buf[cb] complete -> safe to overwrite after barrier
        asm volatile("s_waitcnt lgkmcnt(0)" ::: "memory");
        SB0();
        FENCE(); __builtin_amdgcn_s_barrier(); FENCE();

        // ---- stage K-tile t+2 into buf[cb]; LDS writes hide under Q3/Q4 ----
        if (more) {
            stageA(cb, 0, t + 2); stageA(cb, 1, t + 2);
            stageB(cb, 0, t + 2); stageB(cb, 1, t + 2);
        }
        SB0();

        // ---- Q3: aHi x bLo ----
        __builtin_amdgcn_s_setprio(1);
        #pragma unroll
        for (int mi = 0; mi < 4; ++mi)
            #pragma unroll
            for (int ni = 0; ni < 2; ++ni)
                #pragma unroll
                for (int ks = 0; ks < 2; ++ks)
                    acc[mi + 4][ni] = __builtin_amdgcn_mfma_f32_16x16x32_bf16(
                        aHi[mi][ks], bLo[ni][ks], acc[mi + 4][ni], 0, 0, 0);

        // ---- Q4: aHi x bHi ----
        #pragma unroll
        for (int mi = 0; mi < 4; ++mi)
            #pragma unroll
            for (int ni = 0; ni < 2; ++ni)
                #pragma unroll
                for (int ks = 0; ks < 2; ++ks)
                    acc[mi + 4][ni + 2] = __builtin_amdgcn_mfma_f32_16x16x32_bf16(
                        aHi[mi][ks], bHi[ni][ks], acc[mi + 4][ni + 2], 0, 0, 0);
        __builtin_amdgcn_s_setprio(0);

        // ---- counted drain: K(t+1) landed; K(t+2) stays in flight ----
        if (more) asm volatile("s_waitcnt vmcnt(8)" ::: "memory");
        else      asm volatile("s_waitcnt vmcnt(0)" ::: "memory");
        FENCE(); __builtin_amdgcn_s_barrier(); FENCE();
    }

    int cl = lane & 15;
    int rq = (lane >> 4) * 4;
    #pragma unroll
    for (int mi = 0; mi < 8; ++mi) {
        #pragma unroll
        for (int ni = 0; ni < 4; ++ni) {
            int row = rowA0 + wm * 128 + mi * 16 + rq;
            int col = colB0 + wn * 64 + ni * 16 + cl;
            float* cp = C + (size_t)row * N + col;
            #pragma unroll
            for (int r = 0; r < 4; ++r)
                cp[(size_t)r * N] = acc[mi][ni][r];
        }
    }
}

extern "C" void kernel_launch(void* const* d_in, const int* in_sizes, int n_in,
                              void* d_out, int out_size, void* d_ws, size_t ws_size,
                              hipStream_t stream) {
    const float* x = (const float*)d_in[0];
    const float* w = (const float*)d_in[1];
    float* out = (float*)d_out;

    const int K = 4096;
    const int T = in_sizes[0] / K;   // 8192
    const int O = in_sizes[1] / K;   // 4096

    uint16_t* xq = (uint16_t*)d_ws;
    uint16_t* wq = (uint16_t*)((char*)d_ws + (size_t)T * K * 2);

    quant_kernel<<<2048, 256, 0, stream>>>(x, xq, (T * K) >> 2);
    quant_kernel<<<2048, 256, 0, stream>>>(w, wq, (O * K) >> 2);

    int nwg = (T / BM) * (O / BN);   // 512
    gemm_kernel<<<nwg, 512, 0, stream>>>(xq, wq, out, T, O, K);
}